// Round 1
// baseline (566.775 us; speedup 1.0000x reference)
//
#include <hip/hip_runtime.h>

#define N_NODES 50000
#define N_EDGES 800000
#define N_GRAPHS 64
#define H 64

// ws layout (floats):
//   aggr   [0, N_NODES*H)                      12.8 MB
//   abc    [N_NODES*H, +3*H)                   A[64] B[64] C[64]
//   gsum   [.., +N_GRAPHS)
//   gcnt   [.., +N_GRAPHS)
#define AGGR_OFF   0
#define ABC_OFF    (N_NODES * H)
#define GSUM_OFF   (ABC_OFF + 3 * H)
#define GCNT_OFF   (GSUM_OFF + N_GRAPHS)

// ---------------------------------------------------------------------------
// k_init: zero aggr (vectorized) and compute folded coefficients A,B,C.
__global__ __launch_bounds__(256) void k_init(
    float4* __restrict__ aggr4,           // N_NODES*H/4 float4
    float* __restrict__ abc,
    float* __restrict__ gsum, float* __restrict__ gcnt,
    const float* __restrict__ Wn, const float* __restrict__ bn,
    const float* __restrict__ We, const float* __restrict__ be,
    const float* __restrict__ Wm, const float* __restrict__ bm)
{
    const int tid = blockIdx.x * blockDim.x + threadIdx.x;
    const int nthreads = gridDim.x * blockDim.x;
    const int n4 = (N_NODES * H) / 4;
    for (int i = tid; i < n4; i += nthreads)
        aggr4[i] = make_float4(0.f, 0.f, 0.f, 0.f);

    if (blockIdx.x == 0 && threadIdx.x < H) {
        const int k = threadIdx.x;
        float a = 0.f, b = 0.f, c = 0.f;
        #pragma unroll
        for (int i = 0; i < H; ++i) {
            float wt = Wm[i * H + k];          // top half: multiplies x_j encoding
            float wb = Wm[(H + i) * H + k];    // bottom half: multiplies edge encoding
            a = fmaf(Wn[i], wt, a);
            b = fmaf(We[i], wb, b);
            c = fmaf(bn[i], wt, c);
            c = fmaf(be[i], wb, c);
        }
        abc[k]         = a;
        abc[H + k]     = b;
        abc[2 * H + k] = c + bm[k];
        if (k < N_GRAPHS) { gsum[k] = 0.f; gcnt[k] = 0.f; }
    }
}

// ---------------------------------------------------------------------------
// k_edge: wave processes 64 edges; lane k owns hidden component k.
__global__ __launch_bounds__(256) void k_edge(
    const float* __restrict__ x, const float* __restrict__ ea,
    const int* __restrict__ ei, const float* __restrict__ abc,
    float* __restrict__ aggr)
{
    const int lane  = threadIdx.x & 63;
    const int gwave = (blockIdx.x * blockDim.x + threadIdx.x) >> 6;
    const int nwave = (gridDim.x * blockDim.x) >> 6;

    const float A = abc[lane];
    const float B = abc[H + lane];
    const float C = abc[2 * H + lane];

    const int* __restrict__ src = ei;
    const int* __restrict__ dst = ei + N_EDGES;

    for (int e0 = gwave * 64; e0 < N_EDGES; e0 += nwave * 64) {
        const int e = e0 + lane;
        int   d  = 0;
        float av = 0.f, xv = 0.f;
        if (e < N_EDGES) {
            const int s = src[e];
            d  = dst[e];
            av = ea[e];
            xv = x[s];
        }
        const int cnt = min(64, N_EDGES - e0);
        for (int j = 0; j < cnt; ++j) {
            const float xj = __shfl(xv, j);
            const float aj = __shfl(av, j);
            const int   dj = __shfl(d,  j);
            const float m  = fmaxf(fmaf(xj, A, fmaf(aj, B, C)), 0.f);
            atomicAdd(&aggr[dj * H + lane], m);
        }
    }
}

// ---------------------------------------------------------------------------
// k_node: one wave per node. t = aggr[n] @ W_upd; s = relu(t+bu)·W_out;
// atomic into per-graph sum + count.
__global__ __launch_bounds__(256) void k_node(
    const float* __restrict__ aggr, const int* __restrict__ batch,
    const float* __restrict__ Wu, const float* __restrict__ bu,
    const float* __restrict__ Wo,
    float* __restrict__ gsum, float* __restrict__ gcnt)
{
    __shared__ float sWu[H * H];   // 16 KB
    for (int i = threadIdx.x; i < H * H; i += blockDim.x) sWu[i] = Wu[i];
    __syncthreads();

    const int lane  = threadIdx.x & 63;
    const int gwave = (blockIdx.x * blockDim.x + threadIdx.x) >> 6;
    const int nwave = (gridDim.x * blockDim.x) >> 6;

    const float bul = bu[lane];
    const float wol = Wo[lane];

    for (int n = gwave; n < N_NODES; n += nwave) {
        const float a = aggr[n * H + lane];
        float t = 0.f;
        #pragma unroll
        for (int i = 0; i < H; ++i)
            t = fmaf(__shfl(a, i), sWu[i * H + lane], t);

        float u = fmaxf(t + bul, 0.f) * wol;
        #pragma unroll
        for (int off = 32; off > 0; off >>= 1)
            u += __shfl_down(u, off);

        if (lane == 0) {
            const int g = batch[n];
            atomicAdd(&gsum[g], u);
            atomicAdd(&gcnt[g], 1.f);
        }
    }
}

// ---------------------------------------------------------------------------
__global__ void k_final(const float* __restrict__ gsum,
                        const float* __restrict__ gcnt,
                        const float* __restrict__ bo,
                        float* __restrict__ out)
{
    const int g = threadIdx.x;
    if (g < N_GRAPHS)
        out[g] = gsum[g] / fmaxf(gcnt[g], 1.f) + bo[0];
}

// ---------------------------------------------------------------------------
extern "C" void kernel_launch(void* const* d_in, const int* in_sizes, int n_in,
                              void* d_out, int out_size, void* d_ws, size_t ws_size,
                              hipStream_t stream)
{
    const float* x      = (const float*)d_in[0];
    const float* ea     = (const float*)d_in[1];
    const int*   ei     = (const int*)  d_in[2];
    const int*   batch  = (const int*)  d_in[3];
    const float* Wn     = (const float*)d_in[4];
    const float* bn     = (const float*)d_in[5];
    const float* We     = (const float*)d_in[6];
    const float* be     = (const float*)d_in[7];
    const float* Wm     = (const float*)d_in[8];
    const float* bm     = (const float*)d_in[9];
    const float* Wu     = (const float*)d_in[10];
    const float* bu     = (const float*)d_in[11];
    const float* Wo     = (const float*)d_in[12];
    const float* bo     = (const float*)d_in[13];

    float* ws   = (float*)d_ws;
    float* aggr = ws + AGGR_OFF;
    float* abc  = ws + ABC_OFF;
    float* gsum = ws + GSUM_OFF;
    float* gcnt = ws + GCNT_OFF;
    float* out  = (float*)d_out;

    // 1. zero aggr + fold weights
    k_init<<<2048, 256, 0, stream>>>((float4*)aggr, abc, gsum, gcnt,
                                     Wn, bn, We, be, Wm, bm);

    // 2. edge pass: 800000/64 = 12500 waves = 3125 blocks of 4 waves
    k_edge<<<3125, 256, 0, stream>>>(x, ea, ei, abc, aggr);

    // 3. node pass: grid-stride, one wave per node per iteration
    k_node<<<1024, 256, 0, stream>>>(aggr, batch, Wu, bu, Wo, gsum, gcnt);

    // 4. finalize
    k_final<<<1, 64, 0, stream>>>(gsum, gcnt, bo, out);
}

// Round 2
// 216.133 us; speedup vs baseline: 2.6223x; 2.6223x over previous
//
#include <hip/hip_runtime.h>

#define N_NODES 50000
#define N_EDGES 800000
#define N_GRAPHS 64
#define H 64

// ws layout (floats):
#define AGGR_OFF   0
#define ABC_OFF    (N_NODES * H)
#define WUT_OFF    (ABC_OFF + 3 * H)
#define GSUM_OFF   (WUT_OFF + H * H)
#define GCNT_OFF   (GSUM_OFF + N_GRAPHS)

// ---------------------------------------------------------------------------
// k_init: zero aggr, fold A/B/C coefficients, transpose W_upd, zero gsum/gcnt.
__global__ __launch_bounds__(256) void k_init(
    float4* __restrict__ aggr4,
    float* __restrict__ abc, float* __restrict__ wut,
    float* __restrict__ gsum, float* __restrict__ gcnt,
    const float* __restrict__ Wn, const float* __restrict__ bn,
    const float* __restrict__ We, const float* __restrict__ be,
    const float* __restrict__ Wm, const float* __restrict__ bm,
    const float* __restrict__ Wu)
{
    const int tid = blockIdx.x * blockDim.x + threadIdx.x;
    const int nthreads = gridDim.x * blockDim.x;
    const int n4 = (N_NODES * H) / 4;
    for (int i = tid; i < n4; i += nthreads)
        aggr4[i] = make_float4(0.f, 0.f, 0.f, 0.f);

    if (blockIdx.x == 0 && threadIdx.x < H) {
        const int k = threadIdx.x;
        float a = 0.f, b = 0.f, c = 0.f;
        #pragma unroll
        for (int i = 0; i < H; ++i) {
            float wt = Wm[i * H + k];
            float wb = Wm[(H + i) * H + k];
            a = fmaf(Wn[i], wt, a);
            b = fmaf(We[i], wb, b);
            c = fmaf(bn[i], wt, c);
            c = fmaf(be[i], wb, c);
        }
        abc[k]         = a;
        abc[H + k]     = b;
        abc[2 * H + k] = c + bm[k];
        if (k < N_GRAPHS) { gsum[k] = 0.f; gcnt[k] = 0.f; }
    }
    // transpose W_upd: WuT[k][i] = Wu[i][k]
    if (blockIdx.x == 1) {
        for (int idx = threadIdx.x; idx < H * H; idx += blockDim.x) {
            const int i = idx >> 6, k = idx & 63;
            wut[k * H + i] = Wu[i * H + k];
        }
    }
}

// ---------------------------------------------------------------------------
// k_edge: wave processes 64 edges; lane k owns hidden component k.
__global__ __launch_bounds__(256) void k_edge(
    const float* __restrict__ x, const float* __restrict__ ea,
    const int* __restrict__ ei, const float* __restrict__ abc,
    float* __restrict__ aggr)
{
    const int lane  = threadIdx.x & 63;
    const int gwave = (blockIdx.x * blockDim.x + threadIdx.x) >> 6;

    const float A = abc[lane];
    const float B = abc[H + lane];
    const float C = abc[2 * H + lane];

    const int* __restrict__ src = ei;
    const int* __restrict__ dst = ei + N_EDGES;

    const int e0 = gwave * 64;
    if (e0 >= N_EDGES) return;
    const int e = e0 + lane;
    const int s = src[e];
    const int d = dst[e];
    const float av = ea[e];
    const float xv = x[s];

    #pragma unroll 8
    for (int j = 0; j < 64; ++j) {
        const float xj = __shfl(xv, j);
        const float aj = __shfl(av, j);
        const int   dj = __shfl(d,  j);
        const float m  = fmaxf(fmaf(xj, A, fmaf(aj, B, C)), 0.f);
        atomicAdd(&aggr[dj * H + lane], m);
    }
}

// ---------------------------------------------------------------------------
// k_node: lane-per-node. a[] in registers; WuT/bu/Wo are wave-uniform reads
// (scalar loads). Per-graph reduce via LDS atomics, then one global atomic
// per block per graph.
__global__ __launch_bounds__(256) void k_node(
    const float* __restrict__ aggr, const int* __restrict__ batch,
    const float* __restrict__ wut, const float* __restrict__ bu,
    const float* __restrict__ Wo,
    float* __restrict__ gsum, float* __restrict__ gcnt)
{
    __shared__ float lsum[N_GRAPHS];
    __shared__ float lcnt[N_GRAPHS];
    if (threadIdx.x < N_GRAPHS) { lsum[threadIdx.x] = 0.f; lcnt[threadIdx.x] = 0.f; }
    __syncthreads();

    const int n = blockIdx.x * blockDim.x + threadIdx.x;
    if (n < N_NODES) {
        float4 a4[16];
        const float4* __restrict__ ap = (const float4*)(aggr + n * H);
        #pragma unroll
        for (int i = 0; i < 16; ++i) a4[i] = ap[i];

        float s = 0.f;
        for (int k = 0; k < H; ++k) {
            const float4* __restrict__ w4 = (const float4*)(wut + k * H);
            float t0 = 0.f, t1 = 0.f, t2 = 0.f, t3 = 0.f;
            #pragma unroll
            for (int i = 0; i < 16; i += 4) {
                float4 w;
                w = w4[i + 0]; t0 = fmaf(a4[i+0].x, w.x, t0); t0 = fmaf(a4[i+0].y, w.y, t0);
                               t0 = fmaf(a4[i+0].z, w.z, t0); t0 = fmaf(a4[i+0].w, w.w, t0);
                w = w4[i + 1]; t1 = fmaf(a4[i+1].x, w.x, t1); t1 = fmaf(a4[i+1].y, w.y, t1);
                               t1 = fmaf(a4[i+1].z, w.z, t1); t1 = fmaf(a4[i+1].w, w.w, t1);
                w = w4[i + 2]; t2 = fmaf(a4[i+2].x, w.x, t2); t2 = fmaf(a4[i+2].y, w.y, t2);
                               t2 = fmaf(a4[i+2].z, w.z, t2); t2 = fmaf(a4[i+2].w, w.w, t2);
                w = w4[i + 3]; t3 = fmaf(a4[i+3].x, w.x, t3); t3 = fmaf(a4[i+3].y, w.y, t3);
                               t3 = fmaf(a4[i+3].z, w.z, t3); t3 = fmaf(a4[i+3].w, w.w, t3);
            }
            const float t = (t0 + t1) + (t2 + t3);
            s = fmaf(fmaxf(t + bu[k], 0.f), Wo[k], s);
        }
        const int g = batch[n];
        atomicAdd(&lsum[g], s);
        atomicAdd(&lcnt[g], 1.f);
    }
    __syncthreads();
    if (threadIdx.x < N_GRAPHS) {
        const float ls = lsum[threadIdx.x];
        const float lc = lcnt[threadIdx.x];
        if (lc != 0.f) {
            atomicAdd(&gsum[threadIdx.x], ls);
            atomicAdd(&gcnt[threadIdx.x], lc);
        }
    }
}

// ---------------------------------------------------------------------------
__global__ void k_final(const float* __restrict__ gsum,
                        const float* __restrict__ gcnt,
                        const float* __restrict__ bo,
                        float* __restrict__ out)
{
    const int g = threadIdx.x;
    if (g < N_GRAPHS)
        out[g] = gsum[g] / fmaxf(gcnt[g], 1.f) + bo[0];
}

// ---------------------------------------------------------------------------
extern "C" void kernel_launch(void* const* d_in, const int* in_sizes, int n_in,
                              void* d_out, int out_size, void* d_ws, size_t ws_size,
                              hipStream_t stream)
{
    const float* x      = (const float*)d_in[0];
    const float* ea     = (const float*)d_in[1];
    const int*   ei     = (const int*)  d_in[2];
    const int*   batch  = (const int*)  d_in[3];
    const float* Wn     = (const float*)d_in[4];
    const float* bn     = (const float*)d_in[5];
    const float* We     = (const float*)d_in[6];
    const float* be     = (const float*)d_in[7];
    const float* Wm     = (const float*)d_in[8];
    const float* bm     = (const float*)d_in[9];
    const float* Wu     = (const float*)d_in[10];
    const float* bu     = (const float*)d_in[11];
    const float* Wo     = (const float*)d_in[12];
    const float* bo     = (const float*)d_in[13];

    float* ws   = (float*)d_ws;
    float* aggr = ws + AGGR_OFF;
    float* abc  = ws + ABC_OFF;
    float* wut  = ws + WUT_OFF;
    float* gsum = ws + GSUM_OFF;
    float* gcnt = ws + GCNT_OFF;
    float* out  = (float*)d_out;

    k_init<<<2048, 256, 0, stream>>>((float4*)aggr, abc, wut, gsum, gcnt,
                                     Wn, bn, We, be, Wm, bm, Wu);

    // edge pass: 800000/64 = 12500 waves = 3125 blocks of 4 waves
    k_edge<<<3125, 256, 0, stream>>>(x, ea, ei, abc, aggr);

    // node pass: lane-per-node
    k_node<<<(N_NODES + 255) / 256, 256, 0, stream>>>(aggr, batch, wut, bu, Wo,
                                                      gsum, gcnt);

    k_final<<<1, 64, 0, stream>>>(gsum, gcnt, bo, out);
}

// Round 3
// 181.217 us; speedup vs baseline: 3.1276x; 1.1927x over previous
//
#include <hip/hip_runtime.h>

#define N_NODES 50000
#define N_EDGES 800000
#define N_GRAPHS 64
#define H 64
#define SCAN_BLOCKS ((N_NODES + 255) / 256)   // 196

// ws layout (float units):
#define AGGR_OFF   0
#define ABC_OFF    (AGGR_OFF + N_NODES * H)
#define WUT_OFF    (ABC_OFF + 3 * H)
#define GSUM_OFF   (WUT_OFF + H * H)
#define GCNT_OFF   (GSUM_OFF + N_GRAPHS)
#define CNT_OFF    (GCNT_OFF + N_GRAPHS)          // int[N_NODES]
#define OFF_OFF    (CNT_OFF + N_NODES)            // int[N_NODES + 2] (pad to even)
#define CUR_OFF    (OFF_OFF + N_NODES + 2)        // int[N_NODES]
#define BSUM_OFF   (CUR_OFF + N_NODES)            // int[256]
#define PAIRS_OFF  (BSUM_OFF + 256)               // float2[N_EDGES] (offset is even)

// ---------------------------------------------------------------------------
// k_prep: zero cnt/gsum/gcnt, fold A/B/C, transpose W_upd.
__global__ __launch_bounds__(256) void k_prep(
    int* __restrict__ cnt,
    float* __restrict__ abc, float* __restrict__ wut,
    float* __restrict__ gsum, float* __restrict__ gcnt,
    const float* __restrict__ Wn, const float* __restrict__ bn,
    const float* __restrict__ We, const float* __restrict__ be,
    const float* __restrict__ Wm, const float* __restrict__ bm,
    const float* __restrict__ Wu)
{
    const int tid = blockIdx.x * blockDim.x + threadIdx.x;
    const int nthreads = gridDim.x * blockDim.x;
    for (int i = tid; i < N_NODES; i += nthreads) cnt[i] = 0;

    if (blockIdx.x == 0 && threadIdx.x < H) {
        const int k = threadIdx.x;
        float a = 0.f, b = 0.f, c = 0.f;
        #pragma unroll
        for (int i = 0; i < H; ++i) {
            float wt = Wm[i * H + k];
            float wb = Wm[(H + i) * H + k];
            a = fmaf(Wn[i], wt, a);
            b = fmaf(We[i], wb, b);
            c = fmaf(bn[i], wt, c);
            c = fmaf(be[i], wb, c);
        }
        abc[k]         = a;
        abc[H + k]     = b;
        abc[2 * H + k] = c + bm[k];
        if (k < N_GRAPHS) { gsum[k] = 0.f; gcnt[k] = 0.f; }
    }
    if (blockIdx.x == 1) {
        for (int idx = threadIdx.x; idx < H * H; idx += blockDim.x) {
            const int i = idx >> 6, k = idx & 63;
            wut[k * H + i] = Wu[i * H + k];
        }
    }
}

// ---------------------------------------------------------------------------
// k_hist: degree histogram of dst.
__global__ __launch_bounds__(256) void k_hist(
    const int* __restrict__ ei, int* __restrict__ cnt)
{
    const int tid = blockIdx.x * blockDim.x + threadIdx.x;
    const int nthreads = gridDim.x * blockDim.x;
    const int* __restrict__ dst = ei + N_EDGES;
    for (int e = tid; e < N_EDGES; e += nthreads)
        atomicAdd(&cnt[dst[e]], 1);
}

// ---------------------------------------------------------------------------
// k_scan1: per-block (256-elem) exclusive scan of cnt -> off, block total -> bsum.
__global__ __launch_bounds__(256) void k_scan1(
    const int* __restrict__ cnt, int* __restrict__ off, int* __restrict__ bsum)
{
    __shared__ int s[256];
    const int t = threadIdx.x;
    const int i = blockIdx.x * 256 + t;
    const int v = (i < N_NODES) ? cnt[i] : 0;
    s[t] = v;
    __syncthreads();
    #pragma unroll
    for (int d = 1; d < 256; d <<= 1) {
        const int add = (t >= d) ? s[t - d] : 0;
        __syncthreads();
        s[t] += add;
        __syncthreads();
    }
    if (i < N_NODES) off[i] = s[t] - v;        // exclusive within block
    if (t == 255) bsum[blockIdx.x] = s[255];
}

// ---------------------------------------------------------------------------
// k_scan2: add prefix of block sums; write final offsets into off and cursor.
__global__ __launch_bounds__(256) void k_scan2(
    const int* __restrict__ bsum, int* __restrict__ off, int* __restrict__ cursor)
{
    __shared__ int red[4];
    const int b = blockIdx.x;
    const int t = threadIdx.x;
    int v = (t < b) ? bsum[t] : 0;             // b <= 195 < 256
    #pragma unroll
    for (int o = 32; o > 0; o >>= 1) v += __shfl_down(v, o);
    if ((t & 63) == 0) red[t >> 6] = v;
    __syncthreads();
    const int blockOff = red[0] + red[1] + red[2] + red[3];
    const int i = b * 256 + t;
    if (i < N_NODES) {
        const int o2 = off[i] + blockOff;
        off[i] = o2;
        cursor[i] = o2;
    }
}

// ---------------------------------------------------------------------------
// k_scatter: place (x[src], ea) into dst-sorted position via atomic ticket.
__global__ __launch_bounds__(256) void k_scatter(
    const float* __restrict__ x, const float* __restrict__ ea,
    const int* __restrict__ ei, int* __restrict__ cursor,
    float2* __restrict__ pairs)
{
    const int tid = blockIdx.x * blockDim.x + threadIdx.x;
    const int nthreads = gridDim.x * blockDim.x;
    const int* __restrict__ src = ei;
    const int* __restrict__ dst = ei + N_EDGES;
    for (int e = tid; e < N_EDGES; e += nthreads) {
        const int d = dst[e];
        const int p = atomicAdd(&cursor[d], 1);
        pairs[p] = make_float2(x[src[e]], ea[e]);
    }
}

// ---------------------------------------------------------------------------
// k_aggr: one wave per node; lane k = hidden component k. No atomics.
__global__ __launch_bounds__(256) void k_aggr(
    const float2* __restrict__ pairs, const int* __restrict__ off,
    const int* __restrict__ cnt, const float* __restrict__ abc,
    float* __restrict__ aggr)
{
    const int lane = threadIdx.x & 63;
    const int w = (blockIdx.x * blockDim.x + threadIdx.x) >> 6;
    if (w >= N_NODES) return;

    const float A = abc[lane];
    const float B = abc[H + lane];
    const float C = abc[2 * H + lane];

    const int st = off[w];
    const int c  = cnt[w];
    float s = 0.f;
    for (int j = 0; j < c; ++j) {
        const float2 p = pairs[st + j];
        s += fmaxf(fmaf(p.x, A, fmaf(p.y, B, C)), 0.f);
    }
    aggr[w * H + lane] = s;
}

// ---------------------------------------------------------------------------
// k_node: lane-per-node matvec + relu + dot, LDS-atomic graph reduce.
__global__ __launch_bounds__(256) void k_node(
    const float* __restrict__ aggr, const int* __restrict__ batch,
    const float* __restrict__ wut, const float* __restrict__ bu,
    const float* __restrict__ Wo,
    float* __restrict__ gsum, float* __restrict__ gcnt)
{
    __shared__ float lsum[N_GRAPHS];
    __shared__ float lcnt[N_GRAPHS];
    if (threadIdx.x < N_GRAPHS) { lsum[threadIdx.x] = 0.f; lcnt[threadIdx.x] = 0.f; }
    __syncthreads();

    const int n = blockIdx.x * blockDim.x + threadIdx.x;
    if (n < N_NODES) {
        float4 a4[16];
        const float4* __restrict__ ap = (const float4*)(aggr + n * H);
        #pragma unroll
        for (int i = 0; i < 16; ++i) a4[i] = ap[i];

        float s = 0.f;
        for (int k = 0; k < H; ++k) {
            const float4* __restrict__ w4 = (const float4*)(wut + k * H);
            float t0 = 0.f, t1 = 0.f, t2 = 0.f, t3 = 0.f;
            #pragma unroll
            for (int i = 0; i < 16; i += 4) {
                float4 w;
                w = w4[i + 0]; t0 = fmaf(a4[i+0].x, w.x, t0); t0 = fmaf(a4[i+0].y, w.y, t0);
                               t0 = fmaf(a4[i+0].z, w.z, t0); t0 = fmaf(a4[i+0].w, w.w, t0);
                w = w4[i + 1]; t1 = fmaf(a4[i+1].x, w.x, t1); t1 = fmaf(a4[i+1].y, w.y, t1);
                               t1 = fmaf(a4[i+1].z, w.z, t1); t1 = fmaf(a4[i+1].w, w.w, t1);
                w = w4[i + 2]; t2 = fmaf(a4[i+2].x, w.x, t2); t2 = fmaf(a4[i+2].y, w.y, t2);
                               t2 = fmaf(a4[i+2].z, w.z, t2); t2 = fmaf(a4[i+2].w, w.w, t2);
                w = w4[i + 3]; t3 = fmaf(a4[i+3].x, w.x, t3); t3 = fmaf(a4[i+3].y, w.y, t3);
                               t3 = fmaf(a4[i+3].z, w.z, t3); t3 = fmaf(a4[i+3].w, w.w, t3);
            }
            const float t = (t0 + t1) + (t2 + t3);
            s = fmaf(fmaxf(t + bu[k], 0.f), Wo[k], s);
        }
        const int g = batch[n];
        atomicAdd(&lsum[g], s);
        atomicAdd(&lcnt[g], 1.f);
    }
    __syncthreads();
    if (threadIdx.x < N_GRAPHS) {
        const float ls = lsum[threadIdx.x];
        const float lc = lcnt[threadIdx.x];
        if (lc != 0.f) {
            atomicAdd(&gsum[threadIdx.x], ls);
            atomicAdd(&gcnt[threadIdx.x], lc);
        }
    }
}

// ---------------------------------------------------------------------------
__global__ void k_final(const float* __restrict__ gsum,
                        const float* __restrict__ gcnt,
                        const float* __restrict__ bo,
                        float* __restrict__ out)
{
    const int g = threadIdx.x;
    if (g < N_GRAPHS)
        out[g] = gsum[g] / fmaxf(gcnt[g], 1.f) + bo[0];
}

// ---------------------------------------------------------------------------
extern "C" void kernel_launch(void* const* d_in, const int* in_sizes, int n_in,
                              void* d_out, int out_size, void* d_ws, size_t ws_size,
                              hipStream_t stream)
{
    const float* x      = (const float*)d_in[0];
    const float* ea     = (const float*)d_in[1];
    const int*   ei     = (const int*)  d_in[2];
    const int*   batch  = (const int*)  d_in[3];
    const float* Wn     = (const float*)d_in[4];
    const float* bn     = (const float*)d_in[5];
    const float* We     = (const float*)d_in[6];
    const float* be     = (const float*)d_in[7];
    const float* Wm     = (const float*)d_in[8];
    const float* bm     = (const float*)d_in[9];
    const float* Wu     = (const float*)d_in[10];
    const float* bu     = (const float*)d_in[11];
    const float* Wo     = (const float*)d_in[12];
    const float* bo     = (const float*)d_in[13];

    float* ws    = (float*)d_ws;
    float* aggr  = ws + AGGR_OFF;
    float* abc   = ws + ABC_OFF;
    float* wut   = ws + WUT_OFF;
    float* gsum  = ws + GSUM_OFF;
    float* gcnt  = ws + GCNT_OFF;
    int*   cnt   = (int*)(ws + CNT_OFF);
    int*   off   = (int*)(ws + OFF_OFF);
    int*   cur   = (int*)(ws + CUR_OFF);
    int*   bsum  = (int*)(ws + BSUM_OFF);
    float2* pairs = (float2*)(ws + PAIRS_OFF);
    float* out   = (float*)d_out;

    k_prep<<<64, 256, 0, stream>>>(cnt, abc, wut, gsum, gcnt,
                                   Wn, bn, We, be, Wm, bm, Wu);
    k_hist<<<1024, 256, 0, stream>>>(ei, cnt);
    k_scan1<<<SCAN_BLOCKS, 256, 0, stream>>>(cnt, off, bsum);
    k_scan2<<<SCAN_BLOCKS, 256, 0, stream>>>(bsum, off, cur);
    k_scatter<<<1024, 256, 0, stream>>>(x, ea, ei, cur, pairs);
    k_aggr<<<(N_NODES * 64 + 255) / 256, 256, 0, stream>>>(pairs, off, cnt, abc, aggr);
    k_node<<<(N_NODES + 255) / 256, 256, 0, stream>>>(aggr, batch, wut, bu, Wo,
                                                      gsum, gcnt);
    k_final<<<1, 64, 0, stream>>>(gsum, gcnt, bo, out);
}